// Round 1
// baseline (369.357 us; speedup 1.0000x reference)
//
#include <hip/hip_runtime.h>
#include <hip/hip_bf16.h>
#include <math.h>

#define NBINS 15
#define NB1 1024          // stage-1 blocks
#define BLK 256           // threads per block (4 waves)

// Stage 1: one wave per row. Computes per-row (confidence, correct, bin),
// accumulates per-block bin sums in LDS, writes 45 floats of partials per block.
__global__ __launch_bounds__(BLK) void ece_rows_kernel(
    const float* __restrict__ logits,
    const int*   __restrict__ labels,
    float* __restrict__ partials,   // [gridDim.x][45]
    int N, int C)
{
    __shared__ float sb[3][NBINS];  // [0]=cnt, [1]=conf_sum, [2]=acc_sum

    const int t = threadIdx.x;
    if (t < 3 * NBINS) ((float*)sb)[t] = 0.0f;
    __syncthreads();

    const int lane   = t & 63;
    const int wave   = (blockIdx.x * BLK + t) >> 6;
    const int nwaves = (gridDim.x * BLK) >> 6;
    const int nvec   = (C + 3) >> 2;   // 250 float4 per row for C=1000

    for (int row = wave; row < N; row += nwaves) {
        const float4* __restrict__ rp = (const float4*)(logits + (size_t)row * C);

        // load up to 4 float4 per lane (covers C <= 1024)
        float4 v[4];
        #pragma unroll
        for (int k = 0; k < 4; ++k) {
            int idx = lane + 64 * k;
            if (idx < nvec) {
                v[k] = rp[idx];
            } else {
                v[k] = make_float4(-INFINITY, -INFINITY, -INFINITY, -INFINITY);
            }
        }

        // lane-local max + argmax (first occurrence) in increasing-column order
        float m = v[0].x;
        int   am = lane * 4;
        #pragma unroll
        for (int k = 0; k < 4; ++k) {
            int col = (lane + 64 * k) * 4;
            const float* e = (const float*)&v[k];
            #pragma unroll
            for (int j = 0; j < 4; ++j) {
                float x = e[j];
                if (x > m) { m = x; am = col + j; }
            }
        }

        // lane-local sum of exp(x - m)  (exp(-inf)=0 handles tail)
        float s = 0.0f;
        #pragma unroll
        for (int k = 0; k < 4; ++k) {
            const float* e = (const float*)&v[k];
            #pragma unroll
            for (int j = 0; j < 4; ++j) s += __expf(e[j] - m);
        }

        // wave butterfly reduce (m, s, am): online-softmax merge + first-occurrence argmax
        #pragma unroll
        for (int off = 32; off > 0; off >>= 1) {
            float m2 = __shfl_xor(m, off, 64);
            float s2 = __shfl_xor(s, off, 64);
            int  am2 = __shfl_xor(am, off, 64);
            float nm = fmaxf(m, m2);
            float ns = s * __expf(m - nm) + s2 * __expf(m2 - nm);
            int nam;
            if      (m2 > m) nam = am2;
            else if (m > m2) nam = am;
            else             nam = (am < am2) ? am : am2;
            m = nm; s = ns; am = nam;
        }

        if (lane == 0) {
            float conf = 1.0f / s;             // exp(M-M)/sumexp
            float acc  = (am == labels[row]) ? 1.0f : 0.0f;
            // bin = sum(conf > k/15, k=0..14) - 1 ; conf > 0 always
            int b = 0;
            #pragma unroll
            for (int k = 1; k < NBINS; ++k)
                b += (conf > (float)k * (1.0f / 15.0f)) ? 1 : 0;
            atomicAdd(&sb[0][b], 1.0f);
            atomicAdd(&sb[1][b], conf);
            atomicAdd(&sb[2][b], acc);
        }
    }

    __syncthreads();
    if (t < 3 * NBINS)
        partials[(size_t)blockIdx.x * (3 * NBINS) + t] = ((float*)sb)[t];
}

// Stage 2: reduce [NB1][45] partials in double, compute ece & acc.
__global__ __launch_bounds__(1024) void ece_final_kernel(
    const float* __restrict__ partials, float* __restrict__ out, int nb, int N)
{
    __shared__ double red[3 * NBINS][16];
    const int t = threadIdx.x;
    const int c = t >> 4;     // component 0..63 (use 0..44)
    const int sub = t & 15;

    if (c < 3 * NBINS) {
        double a = 0.0;
        for (int b = sub; b < nb; b += 16)
            a += (double)partials[(size_t)b * (3 * NBINS) + c];
        red[c][sub] = a;
    }
    __syncthreads();
    if (t < 3 * NBINS) {
        double ssum = 0.0;
        #pragma unroll
        for (int i = 0; i < 16; ++i) ssum += red[t][i];
        red[t][0] = ssum;
    }
    __syncthreads();
    if (t == 0) {
        double ece = 0.0, acc = 0.0;
        const double n = (double)N;
        for (int k = 0; k < NBINS; ++k) {
            double cnt = red[k][0];
            double cs  = red[NBINS + k][0];
            double as  = red[2 * NBINS + k][0];
            if (cnt > 0.0) {
                double avg_conf = cs / cnt;
                double avg_acc  = as / cnt;
                double prop     = cnt / n;
                ece += fabs(avg_conf - avg_acc) * prop;
                acc += avg_acc * prop;
            }
        }
        out[0] = (float)(ece * 100.0);
        out[1] = (float)(acc * 100.0);
    }
}

extern "C" void kernel_launch(void* const* d_in, const int* in_sizes, int n_in,
                              void* d_out, int out_size, void* d_ws, size_t ws_size,
                              hipStream_t stream) {
    const float* logits = (const float*)d_in[0];
    const int*   labels = (const int*)d_in[1];
    float* out = (float*)d_out;

    const int N = in_sizes[1];            // 65536
    const int C = in_sizes[0] / N;        // 1000

    float* partials = (float*)d_ws;       // NB1 * 45 floats = 184,320 B

    ece_rows_kernel<<<NB1, BLK, 0, stream>>>(logits, labels, partials, N, C);
    ece_final_kernel<<<1, 1024, 0, stream>>>(partials, out, NB1, N);
}